// Round 4
// baseline (331.612 us; speedup 1.0000x reference)
//
#include <hip/hip_runtime.h>
#include <math.h>

typedef unsigned short u16;
typedef __attribute__((ext_vector_type(8))) short bf16x8;
typedef __attribute__((ext_vector_type(4))) float f32x4;
typedef __attribute__((ext_vector_type(16))) float f32x16;

// ---- workspace layout (u16 elements) ----
constexpr int OFF_W1 = 0;        // [3][128][128] (l,h,c)   B for GEMM1, K-major c
constexpr int OFF_W2 = 49152;    // [3][128][128] (l,c,h)   B for GEMM2, K-major h
constexpr int OFF_GW = 98304;    // [256][128]    (o,h)     B for swiglu, K-major h
constexpr int OFF_TG = 131072;   // [64][16]  tg[a][m], zero pad a>=42 / m>=9
constexpr int OFF_FG = 132096;   // [32][48]  fg[m][a], zero pad m>=9 / a>=42
// total 134400 u16 = 268800 bytes

__device__ __forceinline__ u16 f2bf(float f) {
    unsigned u = __float_as_uint(f);
    u += 0x7FFFu + ((u >> 16) & 1u);   // RNE
    return (u16)(u >> 16);
}
__device__ __forceinline__ void st4bf(void* p, f32x4 v) {
    union { unsigned long long u; unsigned int w[2]; } d;
    d.w[0] = (unsigned)f2bf(v[0]) | ((unsigned)f2bf(v[1]) << 16);
    d.w[1] = (unsigned)f2bf(v[2]) | ((unsigned)f2bf(v[3]) << 16);
    *(unsigned long long*)p = d.u;
}

__global__ void prep_kernel(const float* __restrict__ w1, const float* __restrict__ gw,
                            const float* __restrict__ w2, const float* __restrict__ tg,
                            const float* __restrict__ fg, u16* __restrict__ wsb) {
    const int idx = blockIdx.x * blockDim.x + threadIdx.x;
    const int str = gridDim.x * blockDim.x;
    for (int i = idx; i < 49152; i += str) wsb[OFF_W1 + i] = f2bf(w1[i]);
    for (int i = idx; i < 49152; i += str) wsb[OFF_W2 + i] = f2bf(w2[i]);
    for (int i = idx; i < 32768; i += str) wsb[OFF_GW + i] = f2bf(gw[i]);
    for (int i = idx; i < 1024; i += str) {
        int a = i >> 4, m = i & 15;
        wsb[OFF_TG + i] = (a < 42 && m < 9) ? f2bf(tg[a * 9 + m]) : (u16)0;
    }
    for (int i = idx; i < 1536; i += str) {
        int m = i / 48, a = i - m * 48;
        wsb[OFF_FG + i] = (m < 9 && a < 42) ? f2bf(fg[m * 42 + a]) : (u16)0;
    }
}

#define MFMA16(A, B, C) __builtin_amdgcn_mfma_f32_16x16x32_bf16(A, B, C, 0, 0, 0)
#define MFMA32(A, B, C) __builtin_amdgcn_mfma_f32_32x32x16_bf16(A, B, C, 0, 0, 0)

// 2 nodes / 256-thread WG.  Batched row' space (48 rows):
//   l0: row nd (nd=0,1) ; l1: 16 + nd*3 + mm ; l2: 32 + nd*5 + mm
// LDS ~50.2 KB -> 3 WG/CU (12 waves/CU).
__global__ __launch_bounds__(256, 3) void eqffn3(
    const float* __restrict__ x, const float* __restrict__ nwf,
    const float* __restrict__ b1f, const float* __restrict__ gbf,
    const float* __restrict__ b2f, const u16* __restrict__ wsb,
    float* __restrict__ out, int N)
{
    __shared__ __align__(16) u16 A1[48 * 136];     // packed acts, later h2[row'][h]
    __shared__ __align__(16) u16 H1T[2 * 128 * 16]; // h1T[nd][h][m-pad16]
    __shared__ __align__(16) u16 Gg[48 * 136];      // g[a][h] (current node)
    __shared__ __align__(16) u16 G2T[128 * 56];     // g2T[o][a-pad48(+8)] (current node)
    __shared__ float sh_nw[384];
    __shared__ float sh_red[4];

    const int tid  = threadIdx.x;
    const int w    = tid >> 6;        // wave 0..3
    const int lane = tid & 63;
    const int q    = lane >> 4;       // 16x16 quad
    const int r    = lane & 15;
    const int r32  = lane & 31;       // 32x32 lane row/col
    const int half = lane >> 5;
    const int n0   = blockIdx.x * 2;

    // ---- init: zero H1T (NaN safety for pad cols / invalid node), stage nw ----
    {
        unsigned long long* z = (unsigned long long*)H1T;
        for (int i = tid; i < 1024; i += 256) z[i] = 0ull;
    }
    for (int i = tid; i < 384; i += 256) sh_nw[i] = nwf[i];

    // hoisted global bias scalars (L2-hot, latency overlapped with phase A)
    float b1v[2], b2v[2], gbL[2], gbH[2];
    #pragma unroll
    for (int t = 0; t < 2; ++t) {
        const int col = w * 32 + t * 16 + r;
        b1v[t] = b1f[col];
        b2v[t] = b2f[col];
        gbL[t] = gbf[col];
        gbH[t] = gbf[128 + col];
    }
    __syncthreads();

    // ---- phase A: wave-pair (nd = tid>>7) loads node n0+nd, RMS, pack -> A1 ----
    const int nd   = tid >> 7;        // node slot 0/1
    const int pl   = tid & 127;       // lane within pair
    const int myn  = n0 + nd;
    const bool valid = (myn < N);
    float4 xv[3];
    int   nv = 0;
    float ss = 0.f;
    if (valid) {
        const float4* xr = (const float4*)(x + (size_t)myn * 1152);
        for (int i = pl; i < 288; i += 128, ++nv) {
            float4 v = xr[i]; xv[nv] = v;
            ss += v.x * v.x + v.y * v.y + v.z * v.z + v.w * v.w;
        }
    }
    #pragma unroll
    for (int off = 32; off; off >>= 1) ss += __shfl_xor(ss, off);
    if (lane == 0) sh_red[w] = ss;
    __syncthreads();
    const float inv = 1.0f / sqrtf((sh_red[nd * 2] + sh_red[nd * 2 + 1]) * (1.0f / 1152.0f) + 1e-6f);

    if (valid) {
        for (int ii = 0, i = pl; ii < nv; ++ii, i += 128) {
            float4 v = xv[ii];
            #pragma unroll
            for (int e = 0; e < 4; ++e) {
                const int f = i * 4 + e;
                const float val = ((const float*)&v)[e] * inv;
                int row, c, l;
                if (f < 128)      { l = 0; c = f;                        row = nd; }
                else if (f < 512) { int t = f - 128; l = 1; c = t / 3;   row = 16 + nd * 3 + (t - c * 3); }
                else              { int t = f - 512; l = 2; c = t / 5;   row = 32 + nd * 5 + (t - c * 5); }
                A1[row * 136 + c] = f2bf(val * sh_nw[l * 128 + c]);
            }
        }
    }
    __syncthreads();

    // ---- GEMM1: C[row'48][h128], K=c128; A=A1, B=W1[l(Mt)]; -> H1T[nd][h][m] ----
    {
        f32x4 acc[3][2];
        #pragma unroll
        for (int a = 0; a < 3; ++a)
            #pragma unroll
            for (int b = 0; b < 2; ++b)
                #pragma unroll
                for (int e = 0; e < 4; ++e) acc[a][b][e] = 0.f;
        #pragma unroll
        for (int kk = 0; kk < 4; ++kk) {
            bf16x8 af[3];
            #pragma unroll
            for (int Mt = 0; Mt < 3; ++Mt)
                af[Mt] = *(const bf16x8*)&A1[(Mt * 16 + r) * 136 + kk * 32 + q * 8];
            #pragma unroll
            for (int nt = 0; nt < 2; ++nt) {
                const int h = w * 32 + nt * 16 + r;
                #pragma unroll
                for (int Mt = 0; Mt < 3; ++Mt) {
                    bf16x8 bf = *(const bf16x8*)&wsb[OFF_W1 + (Mt * 128 + h) * 128 + kk * 32 + q * 8];
                    acc[Mt][nt] = MFMA16(af[Mt], bf, acc[Mt][nt]);
                }
            }
        }
        #pragma unroll
        for (int nt = 0; nt < 2; ++nt) {
            const int h = w * 32 + nt * 16 + r;
            #pragma unroll
            for (int Mt = 0; Mt < 3; ++Mt) {
                #pragma unroll
                for (int rg = 0; rg < 4; ++rg) {
                    const int rr = q * 4 + rg;
                    const float v = acc[Mt][nt][rg];
                    if (Mt == 0) {
                        if (rr < 2) H1T[rr * 2048 + h * 16 + 0] = f2bf(v + b1v[nt]);
                    } else if (Mt == 1) {
                        if (rr < 6) { int d = rr / 3, mm = rr - d * 3; H1T[d * 2048 + h * 16 + 1 + mm] = f2bf(v); }
                    } else {
                        if (rr < 10) { int d = rr / 5, mm = rr - d * 5; H1T[d * 2048 + h * 16 + 4 + mm] = f2bf(v); }
                    }
                }
            }
        }
    }
    __syncthreads();

    // ---- per-node grid pipeline ----
    for (int n = 0; n < 2; ++n) {
        // to_grid (32x32x16): C=g[a][h]; A=TG[a][m], B=h1T[n][h][m]; wave w -> h block
        {
            const int h = w * 32 + r32;
            bf16x8 bfr = *(const bf16x8*)&H1T[n * 2048 + h * 16 + half * 8];
            bf16x8 a0  = *(const bf16x8*)&wsb[OFF_TG + r32 * 16 + half * 8];
            bf16x8 a1  = *(const bf16x8*)&wsb[OFF_TG + (32 + r32) * 16 + half * 8];
            f32x16 ac0, ac1;
            #pragma unroll
            for (int e = 0; e < 16; ++e) { ac0[e] = 0.f; ac1[e] = 0.f; }
            ac0 = MFMA32(a0, bfr, ac0);
            ac1 = MFMA32(a1, bfr, ac1);
            #pragma unroll
            for (int rg = 0; rg < 16; ++rg) {
                const int ar = (rg & 3) + 8 * (rg >> 2) + 4 * half;
                Gg[ar * 136 + h] = f2bf(ac0[rg]);               // a rows 0..31
                if (ar < 16) Gg[(32 + ar) * 136 + h] = f2bf(ac1[rg]);  // rows 32..47
            }
        }
        __syncthreads();

        // swiglu (16x16x32): C=z[a48][o256], K=h128; A=Gg, B=GW; silu -> G2T[o][a]
        {
            f32x4 aL[2][3], aH[2][3];
            #pragma unroll
            for (int p = 0; p < 2; ++p)
                #pragma unroll
                for (int Mt = 0; Mt < 3; ++Mt)
                    #pragma unroll
                    for (int e = 0; e < 4; ++e) { aL[p][Mt][e] = 0.f; aH[p][Mt][e] = 0.f; }
            #pragma unroll
            for (int kk = 0; kk < 4; ++kk) {
                bf16x8 ga[3];
                #pragma unroll
                for (int Mt = 0; Mt < 3; ++Mt)
                    ga[Mt] = *(const bf16x8*)&Gg[(Mt * 16 + r) * 136 + kk * 32 + q * 8];
                #pragma unroll
                for (int p = 0; p < 2; ++p) {
                    const int oL = w * 32 + p * 16 + r;
                    bf16x8 bL = *(const bf16x8*)&wsb[OFF_GW + oL * 128 + kk * 32 + q * 8];
                    bf16x8 bH = *(const bf16x8*)&wsb[OFF_GW + (oL + 128) * 128 + kk * 32 + q * 8];
                    #pragma unroll
                    for (int Mt = 0; Mt < 3; ++Mt) {
                        aL[p][Mt] = MFMA16(ga[Mt], bL, aL[p][Mt]);
                        aH[p][Mt] = MFMA16(ga[Mt], bH, aH[p][Mt]);
                    }
                }
            }
            #pragma unroll
            for (int p = 0; p < 2; ++p) {
                const int oL = w * 32 + p * 16 + r;
                #pragma unroll
                for (int Mt = 0; Mt < 3; ++Mt) {
                    f32x4 g;
                    #pragma unroll
                    for (int e = 0; e < 4; ++e) {
                        const float zl = aL[p][Mt][e] + gbL[p];
                        const float zh = aH[p][Mt][e] + gbH[p];
                        g[e] = zl * (1.0f / (1.0f + __expf(-zl))) * zh;
                    }
                    st4bf(&G2T[oL * 56 + Mt * 16 + q * 4], g);  // a>=42 junk killed by FG zeros
                }
            }
        }
        __syncthreads();

        // from_grid (32x32x16, K=48): C=h2[m32][h]; A=FG[m][a], B=G2T[h][a] -> A1 rows
        {
            const int h = w * 32 + r32;
            f32x16 ac;
            #pragma unroll
            for (int e = 0; e < 16; ++e) ac[e] = 0.f;
            #pragma unroll
            for (int kk = 0; kk < 3; ++kk) {
                bf16x8 af = *(const bf16x8*)&wsb[OFF_FG + r32 * 48 + kk * 16 + half * 8];
                bf16x8 bf = *(const bf16x8*)&G2T[h * 56 + kk * 16 + half * 8];
                ac = MFMA32(af, bf, ac);
            }
            #pragma unroll
            for (int rg = 0; rg < 16; ++rg) {
                const int m = (rg & 3) + 8 * (rg >> 2) + 4 * half;
                if (m < 9) {
                    const int row = (m == 0) ? n : ((m < 4) ? (16 + n * 3 + m - 1) : (32 + n * 5 + m - 4));
                    A1[row * 136 + h] = f2bf(ac[rg]);
                }
            }
        }
        __syncthreads();   // G2T/Gg safe to rewrite next node; also orders h2 for GEMM2
    }

    // ---- GEMM2: C[row'48][c128], K=h128; A=A1(h2), B=W2[l(Mt)]; direct stores ----
    {
        f32x4 acc[3][2];
        #pragma unroll
        for (int a = 0; a < 3; ++a)
            #pragma unroll
            for (int b = 0; b < 2; ++b)
                #pragma unroll
                for (int e = 0; e < 4; ++e) acc[a][b][e] = 0.f;
        #pragma unroll
        for (int kk = 0; kk < 4; ++kk) {
            bf16x8 af[3];
            #pragma unroll
            for (int Mt = 0; Mt < 3; ++Mt)
                af[Mt] = *(const bf16x8*)&A1[(Mt * 16 + r) * 136 + kk * 32 + q * 8];
            #pragma unroll
            for (int nt = 0; nt < 2; ++nt) {
                const int c = w * 32 + nt * 16 + r;
                #pragma unroll
                for (int Mt = 0; Mt < 3; ++Mt) {
                    bf16x8 bf = *(const bf16x8*)&wsb[OFF_W2 + (Mt * 128 + c) * 128 + kk * 32 + q * 8];
                    acc[Mt][nt] = MFMA16(af[Mt], bf, acc[Mt][nt]);
                }
            }
        }
        #pragma unroll
        for (int nt = 0; nt < 2; ++nt) {
            const int c = w * 32 + nt * 16 + r;
            #pragma unroll
            for (int Mt = 0; Mt < 3; ++Mt) {
                #pragma unroll
                for (int rg = 0; rg < 4; ++rg) {
                    const int rr = q * 4 + rg;
                    const float v = acc[Mt][nt][rg];
                    if (Mt == 0) {
                        if (rr < 2) { int gn = n0 + rr;
                            if (gn < N) out[(size_t)gn * 1152 + c] = v + b2v[nt]; }
                    } else if (Mt == 1) {
                        if (rr < 6) { int d = rr / 3, mm = rr - d * 3; int gn = n0 + d;
                            if (gn < N) out[(size_t)gn * 1152 + 128 + c * 3 + mm] = v; }
                    } else {
                        if (rr < 10) { int d = rr / 5, mm = rr - d * 5; int gn = n0 + d;
                            if (gn < N) out[(size_t)gn * 1152 + 512 + c * 5 + mm] = v; }
                    }
                }
            }
        }
    }
}

extern "C" void kernel_launch(void* const* d_in, const int* in_sizes, int n_in,
                              void* d_out, int out_size, void* d_ws, size_t ws_size,
                              hipStream_t stream)
{
    const float* x  = (const float*)d_in[0];
    const float* nw = (const float*)d_in[1];
    const float* w1 = (const float*)d_in[2];
    const float* b1 = (const float*)d_in[3];
    const float* gw = (const float*)d_in[4];
    const float* gb = (const float*)d_in[5];
    const float* w2 = (const float*)d_in[6];
    const float* b2 = (const float*)d_in[7];
    const float* tg = (const float*)d_in[8];
    const float* fg = (const float*)d_in[9];
    float* out = (float*)d_out;
    u16* wsb = (u16*)d_ws;

    const int N = in_sizes[0] / 1152;
    prep_kernel<<<128, 256, 0, stream>>>(w1, gw, w2, tg, fg, wsb);
    eqffn3<<<(N + 1) / 2, 256, 0, stream>>>(x, nw, b1, gb, b2, wsb, out, N);
}